// Round 3
// baseline (757.524 us; speedup 1.0000x reference)
//
#include <hip/hip_runtime.h>
#include <hip/hip_bf16.h>
#include <stdint.h>

#define L_ 25
#define E_ 64
#define H_ 8
#define B_ 1000
#define S_ 512
#define GQ 2                       // batch elements per block
#define TPBR (L_ * GQ * 4)         // 200 threads (thread = l,g,j0; owns j0 and j0+4)
#define NSUPER (S_ / 2 + L_ - 1)   // 280 supersteps (2 timesteps each)
#define HS 10                      // padded per-(l,g) stride for hsh/hrsh (floats)
#define XG 20                      // padded per-(l,g) stride for xbuf (floats)

__device__ __forceinline__ float ulo(uint32_t u) { return __uint_as_float(u << 16); }
__device__ __forceinline__ float uhi(uint32_t u) { return __uint_as_float(u & 0xffff0000u); }

__device__ __forceinline__ float toF(float v) { return v; }
__device__ __forceinline__ float toF(__hip_bfloat16 v) { return __bfloat162float(v); }
__device__ __forceinline__ void stP(float* p, float v) { *p = v; }
__device__ __forceinline__ void stP(__hip_bfloat16* p, float v) { *p = __float2bfloat16(v); }

__device__ __forceinline__ void load8f(const __hip_bfloat16* p, float* o) {
  const uint4 v = *(const uint4*)p;
  o[0] = ulo(v.x); o[1] = uhi(v.x); o[2] = ulo(v.y); o[3] = uhi(v.y);
  o[4] = ulo(v.z); o[5] = uhi(v.z); o[6] = ulo(v.w); o[7] = uhi(v.w);
}
__device__ __forceinline__ void load8f(const float* p, float* o) {
  const float4 a = ((const float4*)p)[0];
  const float4 b = ((const float4*)p)[1];
  o[0] = a.x; o[1] = a.y; o[2] = a.z; o[3] = a.w;
  o[4] = b.x; o[5] = b.y; o[6] = b.z; o[7] = b.w;
}

__device__ __forceinline__ float sigmo(float x) {
  x = fminf(fmaxf(x, -30.f), 30.f);
  return 1.f / (1.f + __expf(-x));
}
__device__ __forceinline__ float tanh_(float x) {
  x = fminf(fmaxf(x, -15.f), 15.f);
  const float e = __expf(-2.f * x);
  return (1.f - e) / (1.f + e);
}

// ---------------------------------------------------------------------------
// Kernel 0: dtype probe (fp32 vs bf16 inputs). See R1 notes.
// ---------------------------------------------------------------------------
__global__ void gru_detect(const unsigned short* __restrict__ u16, int* __restrict__ flag) {
  const int i = threadIdx.x;  // 64 threads
  float m = 0.f;
#pragma unroll
  for (int k = 0; k < 4; ++k) {
    const uint32_t u = u16[i * 4 + k];
    float v = fabsf(__uint_as_float(u << 16));
    if (!(v < 1e30f)) v = 1e30f;
    m = fmaxf(m, v);
  }
#pragma unroll
  for (int off = 32; off; off >>= 1) m = fmaxf(m, __shfl_down(m, off, 64));
  if (i == 0) *flag = (m > 2.0f) ? 0 : 1;  // 0 = fp32 inputs, 1 = bf16 inputs
}

// ---------------------------------------------------------------------------
// Kernel 1: layer-0 x-projections. gate = blockIdx.y (wave-uniform W pointer).
// pre[(b*S+t)*24 + gate*8 + j]
// ---------------------------------------------------------------------------
template <typename T, typename PT>
__global__ __launch_bounds__(256) void gru_pre(
    const int* __restrict__ flag, int want,
    const int* __restrict__ x, const T* __restrict__ emb,
    const T* __restrict__ Wz, const T* __restrict__ Wr,
    const T* __restrict__ Wh, PT* __restrict__ pre) {
  if (*flag != want) return;
  const int gate = blockIdx.y;
  const T* W = (gate == 0) ? Wz : ((gate == 1) ? Wr : Wh);
  const int chunk = blockIdx.x * 256 + threadIdx.x;  // < 128000
  const int pos0 = chunk * 4;

  const int4 t4 = *(const int4*)(x + pos0);
  const int tok[4] = {t4.x, t4.y, t4.z, t4.w};

  float acc[4][8];
#pragma unroll
  for (int p = 0; p < 4; ++p)
#pragma unroll
    for (int jj = 0; jj < 8; ++jj) acc[p][jj] = 0.f;

  for (int kb = 0; kb < 8; ++kb) {
    float wf[64];
#pragma unroll
    for (int i = 0; i < 8; ++i) load8f(W + kb * 64 + i * 8, wf + 8 * i);
#pragma unroll
    for (int p = 0; p < 4; ++p) {
      float ef[8];
      load8f(emb + (size_t)tok[p] * E_ + kb * 8, ef);
#pragma unroll
      for (int kk = 0; kk < 8; ++kk)
#pragma unroll
        for (int jj = 0; jj < 8; ++jj)
          acc[p][jj] = fmaf(ef[kk], wf[8 * kk + jj], acc[p][jj]);
    }
  }
#pragma unroll
  for (int p = 0; p < 4; ++p) {
    PT* o = pre + (size_t)(pos0 + p) * 24 + gate * 8;
#pragma unroll
    for (int jj = 0; jj < 8; ++jj) stP(o + jj, acc[p][jj]);
  }
}

// ---------------------------------------------------------------------------
// Kernel 2: recurrence. Superstep s: layer l handles t = 2(s-l), 2(s-l)+1.
// Thread = (l, g, j0) owning hidden j0 and j0+4. Weights in registers.
// hsh/hrsh are wave-local (group of 4 lanes); xbuf handoff needs s_barrier.
// ---------------------------------------------------------------------------
template <typename T, typename PT>
__global__ __launch_bounds__(TPBR, 1) void gru_rec(
    const int* __restrict__ flag, int want,
    const PT* __restrict__ pre,
    const T* __restrict__ Whz0, const T* __restrict__ bz0,
    const T* __restrict__ Whr0, const T* __restrict__ br0,
    const T* __restrict__ WrH0, const T* __restrict__ bH0,
    const T* __restrict__ Wxz, const T* __restrict__ Whz,
    const T* __restrict__ bz, const T* __restrict__ Wxr,
    const T* __restrict__ Whr, const T* __restrict__ br,
    const T* __restrict__ WxH, const T* __restrict__ WrH,
    const T* __restrict__ bH, const T* __restrict__ Why,
    const T* __restrict__ by, T* __restrict__ out) {
  if (*flag != want) return;
  __shared__ float hsh[L_ * GQ * HS];
  __shared__ float hrsh[L_ * GQ * HS];
  __shared__ float xbuf[2 * L_ * GQ * XG];

  const int tid = threadIdx.x;
  const int gi = tid >> 2;   // l*GQ + g, 0..49
  const int j0 = tid & 3;
  const int l = gi >> 1;
  const int g = gi & 1;
  const int b = blockIdx.x * GQ + g;

  for (int i = tid; i < L_ * GQ * HS; i += TPBR) { hsh[i] = 0.f; hrsh[i] = 0.f; }

  // ---- weights into registers: [jj][k], jj=0 -> col j0, jj=1 -> col j0+4 ----
  float wxz[2][8], whz[2][8], wxr[2][8], whr[2][8], wxh[2][8], wrh[2][8];
  float vbz[2], vbr[2], vbh[2];
  if (l == 0) {
#pragma unroll
    for (int jj = 0; jj < 2; ++jj) {
      const int j = j0 + 4 * jj;
#pragma unroll
      for (int k = 0; k < 8; ++k) {
        whz[jj][k] = toF(Whz0[k * 8 + j]);
        whr[jj][k] = toF(Whr0[k * 8 + j]);
        wrh[jj][k] = toF(WrH0[k * 8 + j]);
        wxz[jj][k] = 0.f; wxr[jj][k] = 0.f; wxh[jj][k] = 0.f;
      }
      vbz[jj] = toF(bz0[j]); vbr[jj] = toF(br0[j]); vbh[jj] = toF(bH0[j]);
    }
  } else {
    const int base = (l - 1) * 64;
#pragma unroll
    for (int jj = 0; jj < 2; ++jj) {
      const int j = j0 + 4 * jj;
#pragma unroll
      for (int k = 0; k < 8; ++k) {
        wxz[jj][k] = toF(Wxz[base + k * 8 + j]);
        whz[jj][k] = toF(Whz[base + k * 8 + j]);
        wxr[jj][k] = toF(Wxr[base + k * 8 + j]);
        whr[jj][k] = toF(Whr[base + k * 8 + j]);
        wxh[jj][k] = toF(WxH[base + k * 8 + j]);
        wrh[jj][k] = toF(WrH[base + k * 8 + j]);
      }
      vbz[jj] = toF(bz[(l - 1) * 8 + j]);
      vbr[jj] = toF(br[(l - 1) * 8 + j]);
      vbh[jj] = toF(bH[(l - 1) * 8 + j]);
    }
  }

  // layer-0 precomputed x-projection: current superstep's 12 scalars
  int pb = 0;
  float cz[2][2], cr[2][2], ch[2][2];  // [slot][jj]
  if (l == 0) {
    pb = b * (S_ * 24);
#pragma unroll
    for (int sl = 0; sl < 2; ++sl)
#pragma unroll
      for (int jj = 0; jj < 2; ++jj) {
        const int o = pb + sl * 24 + 4 * jj + j0;
        cz[sl][jj] = toF(pre[o]);
        cr[sl][jj] = toF(pre[o + 8]);
        ch[sl][jj] = toF(pre[o + 16]);
      }
  }

  float* hgw = hsh + gi * HS;
  float* hrg = hrsh + gi * HS;

  __syncthreads();

  for (int s = 0; s < NSUPER; ++s) {
    const int pp = s & 1;
    const unsigned rel = (unsigned)(s - l);
    if (rel < (unsigned)(S_ / 2)) {
      const float* xp = xbuf + (pp ? L_ * GQ * XG : 0) + (gi - GQ) * XG;
      float* xc = xbuf + (pp ? 0 : L_ * GQ * XG) + gi * XG;

      // ---- x-contributions for both timeslots ----
      float az[2][2], ar[2][2], ah[2][2];
      if (l == 0) {
#pragma unroll
        for (int sl = 0; sl < 2; ++sl)
#pragma unroll
          for (int jj = 0; jj < 2; ++jj) {
            az[sl][jj] = vbz[jj] + cz[sl][jj];
            ar[sl][jj] = vbr[jj] + cr[sl][jj];
            ah[sl][jj] = vbh[jj] + ch[sl][jj];
          }
        if (rel + 1 < (unsigned)(S_ / 2)) {  // prefetch next superstep
          const int t2 = ((int)rel + 1) * 2;
#pragma unroll
          for (int sl = 0; sl < 2; ++sl)
#pragma unroll
            for (int jj = 0; jj < 2; ++jj) {
              const int o = pb + (t2 + sl) * 24 + 4 * jj + j0;
              cz[sl][jj] = toF(pre[o]);
              cr[sl][jj] = toF(pre[o + 8]);
              ch[sl][jj] = toF(pre[o + 16]);
            }
        }
      } else {
        float xv0[8], xv1[8];
#pragma unroll
        for (int k = 0; k < 8; ++k) { xv0[k] = xp[k]; xv1[k] = xp[8 + k]; }
#pragma unroll
        for (int jj = 0; jj < 2; ++jj) {
          az[0][jj] = vbz[jj]; ar[0][jj] = vbr[jj]; ah[0][jj] = vbh[jj];
          az[1][jj] = vbz[jj]; ar[1][jj] = vbr[jj]; ah[1][jj] = vbh[jj];
#pragma unroll
          for (int k = 0; k < 8; ++k) {
            az[0][jj] = fmaf(xv0[k], wxz[jj][k], az[0][jj]);
            ar[0][jj] = fmaf(xv0[k], wxr[jj][k], ar[0][jj]);
            ah[0][jj] = fmaf(xv0[k], wxh[jj][k], ah[0][jj]);
            az[1][jj] = fmaf(xv1[k], wxz[jj][k], az[1][jj]);
            ar[1][jj] = fmaf(xv1[k], wxr[jj][k], ar[1][jj]);
            ah[1][jj] = fmaf(xv1[k], wxh[jj][k], ah[1][jj]);
          }
        }
      }

      // ---- cell A (slot 0) ----
      float hv[8];
#pragma unroll
      for (int k = 0; k < 8; ++k) hv[k] = hgw[k];
      float hn0[2];
      {
        float z[2], r[2];
#pragma unroll
        for (int jj = 0; jj < 2; ++jj) {
#pragma unroll
          for (int k = 0; k < 8; ++k) {
            az[0][jj] = fmaf(hv[k], whz[jj][k], az[0][jj]);
            ar[0][jj] = fmaf(hv[k], whr[jj][k], ar[0][jj]);
          }
          z[jj] = sigmo(az[0][jj]);
          r[jj] = sigmo(ar[0][jj]);
        }
        hrg[j0] = hv[j0] * r[0];
        hrg[j0 + 4] = hv[j0 + 4] * r[1];
        __builtin_amdgcn_wave_barrier();
        float hrv[8];
#pragma unroll
        for (int k = 0; k < 8; ++k) hrv[k] = hrg[k];
#pragma unroll
        for (int jj = 0; jj < 2; ++jj) {
#pragma unroll
          for (int k = 0; k < 8; ++k) ah[0][jj] = fmaf(hrv[k], wrh[jj][k], ah[0][jj]);
          const float Hc = tanh_(ah[0][jj]);
          const float own = hv[j0 + 4 * jj];
          hn0[jj] = fmaf(z[jj], Hc - own, own);
        }
        hgw[j0] = hn0[0];
        hgw[j0 + 4] = hn0[1];
        __builtin_amdgcn_wave_barrier();
      }

      // ---- cell B (slot 1) ----
      float hn1[2];
      {
        float hv1[8];
#pragma unroll
        for (int k = 0; k < 8; ++k) hv1[k] = hgw[k];
        float z[2], r[2];
#pragma unroll
        for (int jj = 0; jj < 2; ++jj) {
#pragma unroll
          for (int k = 0; k < 8; ++k) {
            az[1][jj] = fmaf(hv1[k], whz[jj][k], az[1][jj]);
            ar[1][jj] = fmaf(hv1[k], whr[jj][k], ar[1][jj]);
          }
          z[jj] = sigmo(az[1][jj]);
          r[jj] = sigmo(ar[1][jj]);
        }
        hrg[j0] = hn0[0] * r[0];
        hrg[j0 + 4] = hn0[1] * r[1];
        __builtin_amdgcn_wave_barrier();
        float hrv[8];
#pragma unroll
        for (int k = 0; k < 8; ++k) hrv[k] = hrg[k];
#pragma unroll
        for (int jj = 0; jj < 2; ++jj) {
#pragma unroll
          for (int k = 0; k < 8; ++k) ah[1][jj] = fmaf(hrv[k], wrh[jj][k], ah[1][jj]);
          const float Hc = tanh_(ah[1][jj]);
          const float own = hn0[jj];
          hn1[jj] = fmaf(z[jj], Hc - own, own);
        }
        hgw[j0] = hn1[0];
        hgw[j0 + 4] = hn1[1];
        __builtin_amdgcn_wave_barrier();
      }

      // ---- publish both timesteps for layer l+1 ----
      xc[j0] = hn0[0];
      xc[j0 + 4] = hn0[1];
      xc[8 + j0] = hn1[0];
      xc[8 + j0 + 4] = hn1[1];
    }
    __syncthreads();
  }

  // ---- epilogue: h_last and logits ----
  stP(out + B_ + (l * B_ + b) * H_ + j0, hgw[j0]);
  stP(out + B_ + (l * B_ + b) * H_ + j0 + 4, hgw[j0 + 4]);
  if (l == L_ - 1 && j0 == 0) {
    float ssum = toF(by[0]);
#pragma unroll
    for (int k = 0; k < 8; ++k) ssum = fmaf(hgw[k], toF(Why[k]), ssum);
    stP(out + b, ssum);
  }
}

// ---------------------------------------------------------------------------
template <typename T, typename PT>
static void launch_mode(const int* flag, int want, void* const* d_in, PT* pre,
                        T* out, hipStream_t stream) {
  const int* x = (const int*)d_in[0];
  const T* emb = (const T*)d_in[1];
  const T* Wxz0 = (const T*)d_in[2];
  const T* Whz0 = (const T*)d_in[3];
  const T* bz0 = (const T*)d_in[4];
  const T* Wxr0 = (const T*)d_in[5];
  const T* Whr0 = (const T*)d_in[6];
  const T* br0 = (const T*)d_in[7];
  const T* WxH0 = (const T*)d_in[8];
  const T* WrH0 = (const T*)d_in[9];
  const T* bH0 = (const T*)d_in[10];
  const T* Wxz = (const T*)d_in[11];
  const T* Whz = (const T*)d_in[12];
  const T* bz = (const T*)d_in[13];
  const T* Wxr = (const T*)d_in[14];
  const T* Whr = (const T*)d_in[15];
  const T* br = (const T*)d_in[16];
  const T* WxH = (const T*)d_in[17];
  const T* WrH = (const T*)d_in[18];
  const T* bH = (const T*)d_in[19];
  const T* Why = (const T*)d_in[20];
  const T* by = (const T*)d_in[21];

  dim3 preGrid(B_ * S_ / 4 / 256, 3);  // (500, 3)
  gru_pre<T, PT><<<preGrid, 256, 0, stream>>>(flag, want, x, emb, Wxz0, Wxr0, WxH0, pre);
  gru_rec<T, PT><<<B_ / GQ, TPBR, 0, stream>>>(
      flag, want, pre, Whz0, bz0, Whr0, br0, WrH0, bH0, Wxz, Whz, bz, Wxr, Whr,
      br, WxH, WrH, bH, Why, by, out);
}

extern "C" void kernel_launch(void* const* d_in, const int* in_sizes, int n_in,
                              void* d_out, int out_size, void* d_ws, size_t ws_size,
                              hipStream_t stream) {
  int* flag = (int*)d_ws;
  char* preMem = (char*)d_ws + 256;
  const size_t needF = (size_t)B_ * S_ * 24 * sizeof(float) + 256;

  gru_detect<<<1, 64, 0, stream>>>((const unsigned short*)d_in[1], flag);

  if (ws_size >= needF) {
    float* pre = (float*)preMem;
    launch_mode<float, float>(flag, 0, d_in, pre, (float*)d_out, stream);
    launch_mode<__hip_bfloat16, float>(flag, 1, d_in, pre, (__hip_bfloat16*)d_out, stream);
  } else {
    __hip_bfloat16* pre = (__hip_bfloat16*)preMem;
    launch_mode<float, __hip_bfloat16>(flag, 0, d_in, pre, (float*)d_out, stream);
    launch_mode<__hip_bfloat16, __hip_bfloat16>(flag, 1, d_in, pre, (__hip_bfloat16*)d_out, stream);
  }
}

// Round 4
// 544.179 us; speedup vs baseline: 1.3921x; 1.3921x over previous
//
#include <hip/hip_runtime.h>
#include <hip/hip_bf16.h>
#include <stdint.h>

#define L_ 25
#define E_ 64
#define H_ 8
#define B_ 1000
#define S_ 512
#define GQ 4                       // batch elements per block
#define NCELL (L_ * GQ)            // 100 cells per block
#define TPBR (NCELL * 8)           // 800 threads, thread = (cell, j)
#define NSUPER (S_ / 2 + L_ - 1)   // 280 supersteps (2 timesteps each)
#define HS 12                      // per-cell stride hsh/hrsh: 48B, 16B-aligned, banks disjoint
#define XG 20                      // per-cell stride xbuf: 80B, 16B-aligned, 2-way (free)

#define PIN(x) asm volatile("" : "+v"(x))

__device__ __forceinline__ float ulo(uint32_t u) { return __uint_as_float(u << 16); }
__device__ __forceinline__ float uhi(uint32_t u) { return __uint_as_float(u & 0xffff0000u); }

__device__ __forceinline__ float toF(float v) { return v; }
__device__ __forceinline__ float toF(__hip_bfloat16 v) { return __bfloat162float(v); }
__device__ __forceinline__ void stP(float* p, float v) { *p = v; }
__device__ __forceinline__ void stP(__hip_bfloat16* p, float v) { *p = __float2bfloat16(v); }

__device__ __forceinline__ void load8f(const __hip_bfloat16* p, float* o) {
  const uint4 v = *(const uint4*)p;
  o[0] = ulo(v.x); o[1] = uhi(v.x); o[2] = ulo(v.y); o[3] = uhi(v.y);
  o[4] = ulo(v.z); o[5] = uhi(v.z); o[6] = ulo(v.w); o[7] = uhi(v.w);
}
__device__ __forceinline__ void load8f(const float* p, float* o) {
  const float4 a = ((const float4*)p)[0];
  const float4 b = ((const float4*)p)[1];
  o[0] = a.x; o[1] = a.y; o[2] = a.z; o[3] = a.w;
  o[4] = b.x; o[5] = b.y; o[6] = b.z; o[7] = b.w;
}

__device__ __forceinline__ float sigmo(float x) {
  x = fminf(fmaxf(x, -30.f), 30.f);
  return 1.f / (1.f + __expf(-x));
}
__device__ __forceinline__ float tanh_(float x) {
  x = fminf(fmaxf(x, -15.f), 15.f);
  const float e = __expf(-2.f * x);
  return (1.f - e) / (1.f + e);
}

// ---------------------------------------------------------------------------
// Kernel 0: dtype probe (fp32 vs bf16 inputs).
// ---------------------------------------------------------------------------
__global__ void gru_detect(const unsigned short* __restrict__ u16, int* __restrict__ flag) {
  const int i = threadIdx.x;  // 64 threads
  float m = 0.f;
#pragma unroll
  for (int k = 0; k < 4; ++k) {
    const uint32_t u = u16[i * 4 + k];
    float v = fabsf(__uint_as_float(u << 16));
    if (!(v < 1e30f)) v = 1e30f;
    m = fmaxf(m, v);
  }
#pragma unroll
  for (int off = 32; off; off >>= 1) m = fmaxf(m, __shfl_down(m, off, 64));
  if (i == 0) *flag = (m > 2.0f) ? 0 : 1;  // 0 = fp32 inputs, 1 = bf16 inputs
}

// ---------------------------------------------------------------------------
// Kernel 1: layer-0 x-projections, weights staged in LDS (broadcast reads).
// pre[(b*S+t)*24 + gate*8 + j]. Thread = 2 tokens; 1000 blocks x 256.
// ---------------------------------------------------------------------------
template <typename T, typename PT>
__global__ __launch_bounds__(256, 4) void gru_pre(
    const int* __restrict__ flag, int want,
    const int* __restrict__ x, const T* __restrict__ emb,
    const T* __restrict__ Wz, const T* __restrict__ Wr,
    const T* __restrict__ Wh, PT* __restrict__ pre) {
  if (*flag != want) return;
  __shared__ __align__(16) float WL[64 * 24];  // [k][z8 r8 h8], 6 KB
  for (int idx = threadIdx.x; idx < 64 * 24; idx += 256) {
    const int k = idx / 24, c = idx - k * 24;
    const T* src = (c < 8) ? Wz : ((c < 16) ? Wr : Wh);
    WL[idx] = toF(src[k * 8 + (c & 7)]);
  }
  __syncthreads();

  const int pos0 = (blockIdx.x * 256 + threadIdx.x) * 2;  // 2 tokens/thread
  const int2 t2 = *(const int2*)(x + pos0);

  float acc[2][24];
#pragma unroll
  for (int p = 0; p < 2; ++p)
#pragma unroll
    for (int c = 0; c < 24; ++c) acc[p][c] = 0.f;

  for (int kb = 0; kb < 8; ++kb) {
    float e0[8], e1[8];
    load8f(emb + (size_t)t2.x * E_ + kb * 8, e0);
    load8f(emb + (size_t)t2.y * E_ + kb * 8, e1);
#pragma unroll
    for (int k8 = 0; k8 < 8; ++k8) {
      const float* wr = WL + (kb * 8 + k8) * 24;  // 96B stride, 16B-aligned
      float wf[24];
#pragma unroll
      for (int q = 0; q < 6; ++q) {
        const float4 w4 = ((const float4*)wr)[q];
        wf[4 * q] = w4.x; wf[4 * q + 1] = w4.y; wf[4 * q + 2] = w4.z; wf[4 * q + 3] = w4.w;
      }
#pragma unroll
      for (int c = 0; c < 24; ++c) {
        acc[0][c] = fmaf(e0[k8], wf[c], acc[0][c]);
        acc[1][c] = fmaf(e1[k8], wf[c], acc[1][c]);
      }
    }
  }
#pragma unroll
  for (int p = 0; p < 2; ++p) {
    PT* o = pre + (size_t)(pos0 + p) * 24;
#pragma unroll
    for (int c = 0; c < 24; ++c) stP(o + c, acc[p][c]);
  }
}

// ---------------------------------------------------------------------------
// Kernel 2: pipelined recurrence. Superstep s: layer l does t = 2(s-l), +1.
// Thread = (l, g, j); weights PINNED in VGPRs; LDS reads are b128,
// bank-disjoint (HS=12, XG=20). Own-h carried in a register across steps.
// ---------------------------------------------------------------------------
template <typename T, typename PT>
__global__ __launch_bounds__(TPBR, 4) void gru_rec(
    const int* __restrict__ flag, int want,
    const PT* __restrict__ pre,
    const T* __restrict__ Whz0, const T* __restrict__ bz0,
    const T* __restrict__ Whr0, const T* __restrict__ br0,
    const T* __restrict__ WrH0, const T* __restrict__ bH0,
    const T* __restrict__ Wxz, const T* __restrict__ Whz,
    const T* __restrict__ bz, const T* __restrict__ Wxr,
    const T* __restrict__ Whr, const T* __restrict__ br,
    const T* __restrict__ WxH, const T* __restrict__ WrH,
    const T* __restrict__ bH, const T* __restrict__ Why,
    const T* __restrict__ by, T* __restrict__ out) {
  if (*flag != want) return;
  __shared__ __align__(16) float hsh[NCELL * HS];
  __shared__ __align__(16) float hrsh[NCELL * HS];
  __shared__ __align__(16) float xbuf[2 * NCELL * XG];

  const int tid = threadIdx.x;
  const int gi = tid >> 3;   // cell = l*GQ + g, 0..99
  const int j = tid & 7;
  const int l = gi >> 2;
  const int g = gi & 3;
  const int b = blockIdx.x * GQ + g;

  for (int i = tid; i < NCELL * HS; i += TPBR) { hsh[i] = 0.f; hrsh[i] = 0.f; }

  // ---- weight columns into registers (51 floats), then PIN ----
  float wxz[8], whz[8], wxr[8], whr[8], wxh[8], wrh[8];
  float vbz, vbr, vbh;
  if (l == 0) {
#pragma unroll
    for (int k = 0; k < 8; ++k) {
      whz[k] = toF(Whz0[k * 8 + j]);
      whr[k] = toF(Whr0[k * 8 + j]);
      wrh[k] = toF(WrH0[k * 8 + j]);
      wxz[k] = 0.f; wxr[k] = 0.f; wxh[k] = 0.f;
    }
    vbz = toF(bz0[j]); vbr = toF(br0[j]); vbh = toF(bH0[j]);
  } else {
    const int base = (l - 1) * 64;
#pragma unroll
    for (int k = 0; k < 8; ++k) {
      wxz[k] = toF(Wxz[base + k * 8 + j]);
      whz[k] = toF(Whz[base + k * 8 + j]);
      wxr[k] = toF(Wxr[base + k * 8 + j]);
      whr[k] = toF(Whr[base + k * 8 + j]);
      wxh[k] = toF(WxH[base + k * 8 + j]);
      wrh[k] = toF(WrH[base + k * 8 + j]);
    }
    vbz = toF(bz[(l - 1) * 8 + j]);
    vbr = toF(br[(l - 1) * 8 + j]);
    vbh = toF(bH[(l - 1) * 8 + j]);
  }
#pragma unroll
  for (int k = 0; k < 8; ++k) {
    PIN(wxz[k]); PIN(whz[k]); PIN(wxr[k]); PIN(whr[k]); PIN(wxh[k]); PIN(wrh[k]);
  }
  PIN(vbz); PIN(vbr); PIN(vbh);

  // layer-0 precomputed x-projection (register prefetch)
  const PT* ppr = pre + (size_t)b * (S_ * 24) + j;
  float cz0 = 0.f, cr0 = 0.f, ch0 = 0.f, cz1 = 0.f, cr1 = 0.f, ch1 = 0.f;
  if (l == 0) {
    cz0 = toF(ppr[0]);  cr0 = toF(ppr[8]);  ch0 = toF(ppr[16]);
    cz1 = toF(ppr[24]); cr1 = toF(ppr[32]); ch1 = toF(ppr[40]);
  }

  float* hgw = hsh + gi * HS;
  float* hrg = hrsh + gi * HS;
  float* hgwj = hgw + j;
  float* hrgj = hrg + j;
  const int gp = (gi >= GQ) ? (gi - GQ) * XG : 0;
  const float* xpe = xbuf + NCELL * XG + gp;  // read when s even
  const float* xpo = xbuf + gp;               // read when s odd
  float* xce = xbuf + gi * XG;                // write when s even
  float* xco = xbuf + NCELL * XG + gi * XG;   // write when s odd

  float hown = 0.f;  // this thread's h[j], carried across supersteps

  __syncthreads();

  for (int s = 0; s < NSUPER; ++s) {
    const unsigned rel = (unsigned)(s - l);
    if (rel < (unsigned)(S_ / 2)) {
      const float* xp = (s & 1) ? xpo : xpe;
      float* xc = (s & 1) ? xco : xce;

      // ================= cell A (timestep 2*rel) =================
      float az0, ar0, ah0;
      if (l == 0) {
        az0 = vbz + cz0; ar0 = vbr + cr0; ah0 = vbh + ch0;
      } else {
        float xv0[8];
        const float4 xa = ((const float4*)xp)[0];
        const float4 xb = ((const float4*)xp)[1];
        xv0[0] = xa.x; xv0[1] = xa.y; xv0[2] = xa.z; xv0[3] = xa.w;
        xv0[4] = xb.x; xv0[5] = xb.y; xv0[6] = xb.z; xv0[7] = xb.w;
        az0 = vbz; ar0 = vbr; ah0 = vbh;
#pragma unroll
        for (int k = 0; k < 8; ++k) {
          az0 = fmaf(xv0[k], wxz[k], az0);
          ar0 = fmaf(xv0[k], wxr[k], ar0);
          ah0 = fmaf(xv0[k], wxh[k], ah0);
        }
      }
      {
        const float4 h01 = ((const float4*)hgw)[0];
        const float4 h23 = ((const float4*)hgw)[1];
        const float hv[8] = {h01.x, h01.y, h01.z, h01.w, h23.x, h23.y, h23.z, h23.w};
#pragma unroll
        for (int k = 0; k < 8; ++k) {
          az0 = fmaf(hv[k], whz[k], az0);
          ar0 = fmaf(hv[k], whr[k], ar0);
        }
      }
      const float zA = sigmo(az0);
      const float rA = sigmo(ar0);
      *hrgj = hown * rA;
      __builtin_amdgcn_wave_barrier();
      {
        const float4 r01 = ((const float4*)hrg)[0];
        const float4 r23 = ((const float4*)hrg)[1];
        const float hrv[8] = {r01.x, r01.y, r01.z, r01.w, r23.x, r23.y, r23.z, r23.w};
#pragma unroll
        for (int k = 0; k < 8; ++k) ah0 = fmaf(hrv[k], wrh[k], ah0);
      }
      const float hn0 = fmaf(zA, tanh_(ah0) - hown, hown);
      *hgwj = hn0;
      __builtin_amdgcn_wave_barrier();

      // ================= cell B (timestep 2*rel+1) =================
      float az1, ar1, ah1;
      if (l == 0) {
        az1 = vbz + cz1; ar1 = vbr + cr1; ah1 = vbh + ch1;
        if (rel + 1 < (unsigned)(S_ / 2)) {  // prefetch next superstep
          const PT* pn = ppr + (rel + 1) * 48;
          cz0 = toF(pn[0]);  cr0 = toF(pn[8]);  ch0 = toF(pn[16]);
          cz1 = toF(pn[24]); cr1 = toF(pn[32]); ch1 = toF(pn[40]);
        }
      } else {
        float xv1[8];
        const float4 xa = ((const float4*)xp)[2];
        const float4 xb = ((const float4*)xp)[3];
        xv1[0] = xa.x; xv1[1] = xa.y; xv1[2] = xa.z; xv1[3] = xa.w;
        xv1[4] = xb.x; xv1[5] = xb.y; xv1[6] = xb.z; xv1[7] = xb.w;
        az1 = vbz; ar1 = vbr; ah1 = vbh;
#pragma unroll
        for (int k = 0; k < 8; ++k) {
          az1 = fmaf(xv1[k], wxz[k], az1);
          ar1 = fmaf(xv1[k], wxr[k], ar1);
          ah1 = fmaf(xv1[k], wxh[k], ah1);
        }
      }
      {
        const float4 h01 = ((const float4*)hgw)[0];
        const float4 h23 = ((const float4*)hgw)[1];
        const float hv1[8] = {h01.x, h01.y, h01.z, h01.w, h23.x, h23.y, h23.z, h23.w};
#pragma unroll
        for (int k = 0; k < 8; ++k) {
          az1 = fmaf(hv1[k], whz[k], az1);
          ar1 = fmaf(hv1[k], whr[k], ar1);
        }
      }
      const float zB = sigmo(az1);
      const float rB = sigmo(ar1);
      *hrgj = hn0 * rB;
      __builtin_amdgcn_wave_barrier();
      {
        const float4 r01 = ((const float4*)hrg)[0];
        const float4 r23 = ((const float4*)hrg)[1];
        const float hrv[8] = {r01.x, r01.y, r01.z, r01.w, r23.x, r23.y, r23.z, r23.w};
#pragma unroll
        for (int k = 0; k < 8; ++k) ah1 = fmaf(hrv[k], wrh[k], ah1);
      }
      const float hn1 = fmaf(zB, tanh_(ah1) - hn0, hn0);
      *hgwj = hn1;
      __builtin_amdgcn_wave_barrier();
      hown = hn1;

      // publish both timesteps for layer l+1
      xc[j] = hn0;
      xc[8 + j] = hn1;
    }
    __syncthreads();
  }

  // ---- epilogue ----
  stP(out + B_ + (l * B_ + b) * H_ + j, hown);
  if (l == L_ - 1 && j == 0) {
    float ssum = toF(by[0]);
#pragma unroll
    for (int k = 0; k < 8; ++k) ssum = fmaf(hgw[k], toF(Why[k]), ssum);
    stP(out + b, ssum);
  }
}

// ---------------------------------------------------------------------------
template <typename T, typename PT>
static void launch_mode(const int* flag, int want, void* const* d_in, PT* pre,
                        T* out, hipStream_t stream) {
  const int* x = (const int*)d_in[0];
  const T* emb = (const T*)d_in[1];
  const T* Wxz0 = (const T*)d_in[2];
  const T* Whz0 = (const T*)d_in[3];
  const T* bz0 = (const T*)d_in[4];
  const T* Wxr0 = (const T*)d_in[5];
  const T* Whr0 = (const T*)d_in[6];
  const T* br0 = (const T*)d_in[7];
  const T* WxH0 = (const T*)d_in[8];
  const T* WrH0 = (const T*)d_in[9];
  const T* bH0 = (const T*)d_in[10];
  const T* Wxz = (const T*)d_in[11];
  const T* Whz = (const T*)d_in[12];
  const T* bz = (const T*)d_in[13];
  const T* Wxr = (const T*)d_in[14];
  const T* Whr = (const T*)d_in[15];
  const T* br = (const T*)d_in[16];
  const T* WxH = (const T*)d_in[17];
  const T* WrH = (const T*)d_in[18];
  const T* bH = (const T*)d_in[19];
  const T* Why = (const T*)d_in[20];
  const T* by = (const T*)d_in[21];

  gru_pre<T, PT><<<B_ * S_ / 2 / 256, 256, 0, stream>>>(flag, want, x, emb,
                                                        Wxz0, Wxr0, WxH0, pre);
  gru_rec<T, PT><<<B_ / GQ, TPBR, 0, stream>>>(
      flag, want, pre, Whz0, bz0, Whr0, br0, WrH0, bH0, Wxz, Whz, bz, Wxr, Whr,
      br, WxH, WrH, bH, Why, by, out);
}

extern "C" void kernel_launch(void* const* d_in, const int* in_sizes, int n_in,
                              void* d_out, int out_size, void* d_ws, size_t ws_size,
                              hipStream_t stream) {
  int* flag = (int*)d_ws;
  char* preMem = (char*)d_ws + 256;
  const size_t needF = (size_t)B_ * S_ * 24 * sizeof(float) + 256;

  gru_detect<<<1, 64, 0, stream>>>((const unsigned short*)d_in[1], flag);

  if (ws_size >= needF) {
    float* pre = (float*)preMem;
    launch_mode<float, float>(flag, 0, d_in, pre, (float*)d_out, stream);
    launch_mode<__hip_bfloat16, float>(flag, 1, d_in, pre, (__hip_bfloat16*)d_out, stream);
  } else {
    __hip_bfloat16* pre = (__hip_bfloat16*)preMem;
    launch_mode<float, __hip_bfloat16>(flag, 0, d_in, pre, (float*)d_out, stream);
    launch_mode<__hip_bfloat16, __hip_bfloat16>(flag, 1, d_in, pre, (__hip_bfloat16*)d_out, stream);
  }
}